// Round 9
// baseline (151.486 us; speedup 1.0000x reference)
//
#include <hip/hip_runtime.h>

// B=16, M=8, S=100, P=40, A=3, D=128, H=8, HD=16. Inputs fp32, output fp32.
// Algebra: feats = [a0,a1,a2,1] @ W4 (rank-4) =>
//   scores = pts4 @ W4qk (4x8); apool[seg,hj] = softmax-pool of pts4 (K=32);
//   emb_pre = apool @ T + out_b  (T = 32x128 precomputed, MFMA K=32)
// k_all: 800 blocks x 16 segments (R7 config — best measured):
//   pool -> emb MFMA -> LN1 -> FFN MFMA -> LN2. bf16 hi/lo 3-product GEMMs.
// R8 lesson: G=32 (fewer/fatter blocks) regressed — block-level parallelism
// at ~35 KB LDS beats per-wave ILP here.
namespace {
constexpr int Sn = 100;
constexpr int Nn = 12800;               // B*M*S
constexpr int OUT0 = 1638400;           // S*B*M*D
}

using bf16x8 = __attribute__((ext_vector_type(8))) short;
using f32x4  = __attribute__((ext_vector_type(4))) float;
#define MFMA16(a, b, c) __builtin_amdgcn_mfma_f32_16x16x32_bf16((a), (b), (c), 0, 0, 0)

__device__ __forceinline__ unsigned short f2bf(float x) {
  unsigned int u = __float_as_uint(x);
  return (unsigned short)((u + 0x7FFFu + ((u >> 16) & 1u)) >> 16);
}
__device__ __forceinline__ float bf2f(unsigned short h) {
  return __uint_as_float(((unsigned int)h) << 16);
}

// ---------------------------------------------------------------------------
// K0M: merged precompute+repack. 49 blocks x 256 thr.
// Blocks 0..47: repack w1 (128x384) / w2 (384x128) into bf16 hi/lo B-frag
// tiles (16 cols x 32 k; slot [tile][hl][lane][j8], lane=(k/8)*16+n%16).
// Block 48: q -> W4qk (4x8), w4wv (32x16) -> Tf (8 B-frag tiles of T).
// ---------------------------------------------------------------------------
__global__ __launch_bounds__(256) void k0m(
    const float* __restrict__ ms, const float* __restrict__ wq,
    const float* __restrict__ wk, const float* __restrict__ bq,
    const float* __restrict__ bk, const float* __restrict__ lin_w,
    const float* __restrict__ lin_b, const float* __restrict__ wv,
    const float* __restrict__ bv, const float* __restrict__ out_w,
    const float* __restrict__ w1, const float* __restrict__ w2,
    float* __restrict__ W4qk, unsigned short* __restrict__ w1f,
    unsigned short* __restrict__ w2f, unsigned short* __restrict__ Tf) {
  const int t = threadIdx.x;
  if (blockIdx.x < 48) {
    const int gid = blockIdx.x * 256 + t;
    const int tile = gid >> 6, lane = gid & 63;
    const int quad = lane >> 4, n16 = lane & 15;
    unsigned short hi[8], lo[8];
    unsigned short* dst;
    if (tile < 96) {                 // w1: nt 0..23, kk 0..3
      const int nt = tile >> 2, kk = tile & 3;
      const int n = nt * 16 + n16;
#pragma unroll
      for (int j = 0; j < 8; ++j) {
        const int k = kk * 32 + quad * 8 + j;
        const float v = w1[k * 384 + n];
        hi[j] = f2bf(v); lo[j] = f2bf(v - bf2f(hi[j]));
      }
      dst = w1f + (size_t)tile * 1024 + lane * 8;
    } else {                         // w2: nt2 0..7, kk2 0..11
      const int t2 = tile - 96;
      const int nt2 = t2 / 12, kk2 = t2 % 12;
      const int n = nt2 * 16 + n16;
#pragma unroll
      for (int j = 0; j < 8; ++j) {
        const int k = kk2 * 32 + quad * 8 + j;
        const float v = w2[k * 128 + n];
        hi[j] = f2bf(v); lo[j] = f2bf(v - bf2f(hi[j]));
      }
      dst = w2f + (size_t)t2 * 1024 + lane * 8;
    }
#pragma unroll
    for (int j = 0; j < 8; ++j) { dst[j] = hi[j]; dst[512 + j] = lo[j]; }
  } else {
    __shared__ float q[128];
    __shared__ float qk_s[8][128];
    __shared__ float qbk_s[8];
    __shared__ float w4wv_s[32][16];
    if (t < 128) {
      float s = bq[t];
      for (int c = 0; c < 128; ++c) s += ms[c] * wq[c * 128 + t];
      q[t] = s;
    }
    __syncthreads();
    if (t < 128) {
      for (int h = 0; h < 8; ++h) {
        float a = 0.f;
#pragma unroll
        for (int j = 0; j < 16; ++j) a += q[h * 16 + j] * wk[t * 128 + h * 16 + j];
        qk_s[h][t] = a * 0.25f;      // scale folded
      }
    }
    if (t < 8) {
      float b = 0.f;
#pragma unroll
      for (int j = 0; j < 16; ++j) b += q[t * 16 + j] * bk[t * 16 + j];
      qbk_s[t] = b * 0.25f;
    }
    __syncthreads();
    if (t < 32) {
      const int j = t >> 3, h = t & 7;
      float s = 0.f;
      for (int c = 0; c < 128; ++c) {
        const float w4 = (j < 3) ? lin_w[j * 128 + c] : lin_b[c];
        s += w4 * qk_s[h][c];
      }
      if (j == 3) s += qbk_s[h];     // qbk folds (pts4[3]==1)
      W4qk[j * 8 + h] = s;
    }
    // w4wv[hj][e] = W4[j] . wv[:, h*16+e]  (+bv fold at j==3)
#pragma unroll
    for (int ii = t * 2; ii < t * 2 + 2; ++ii) {
      const int hj = ii >> 4, e = ii & 15, j = hj & 3, h = hj >> 2;
      float s = 0.f;
      for (int c = 0; c < 128; ++c) {
        const float w4 = (j < 3) ? lin_w[j * 128 + c] : lin_b[c];
        s += w4 * wv[c * 128 + h * 16 + e];
      }
      if (j == 3) s += bv[h * 16 + e];
      w4wv_s[hj][e] = s;
    }
    __syncthreads();
    // Tf: T[hj][col] = w4wv[hj] . out_w[h*16.., col], repacked hi/lo B-frag
    for (int i = t; i < 4096; i += 256) {
      const int hj = i >> 7, col = i & 127, h = hj >> 2;
      float v = 0.f;
#pragma unroll
      for (int e = 0; e < 16; ++e) v += w4wv_s[hj][e] * out_w[(h * 16 + e) * 128 + col];
      const unsigned short hh = f2bf(v), hl = f2bf(v - bf2f(hh));
      const int nt = col >> 4, lane = ((hj >> 3) << 4) + (col & 15), j = hj & 7;
      Tf[(size_t)nt * 1024 + lane * 8 + j] = hh;
      Tf[(size_t)nt * 1024 + 512 + lane * 8 + j] = hl;
    }
  }
}

// ---------------------------------------------------------------------------
// K_ALL: fully fused. 800 blocks x 256 thr, 16 segments each (R7 config).
// pool (VALU) -> emb = apool@Tf (MFMA,K=32) + LN1 -> FFN MFMA + LN2 -> out.
// ---------------------------------------------------------------------------
__global__ __launch_bounds__(256) void k_all(
    const float* __restrict__ roads, const float* __restrict__ W4qk_g,
    const unsigned short* __restrict__ Tf, const float* __restrict__ out_b,
    const float* __restrict__ ln1_g, const float* __restrict__ ln1_b,
    const unsigned short* __restrict__ w1f, const unsigned short* __restrict__ w2f,
    const float* __restrict__ b1, const float* __restrict__ b2,
    const float* __restrict__ ln2_g, const float* __restrict__ ln2_b,
    float* __restrict__ out) {
  const int t = threadIdx.x;
  const int n0 = blockIdx.x * 16;

  __shared__ union {
    float4 pts[640];                         // 10 KB (dead after pool)
    __align__(16) unsigned short A2[24576];  // hidden 16x384 hi/lo, 48 KB... 24 KB
  } u;
  __shared__ __align__(16) unsigned short A1[4096];   // emb 16x128 hi/lo, 8 KB
  __shared__ __align__(16) unsigned short ApF[1024];  // apool 16x32 hi/lo, 2 KB
  __shared__ float w4qk_l[32];
  __shared__ float lnr[16][4][2];

  // ---- stage pts + folded QK
  for (int i = t; i < 640; i += 256)
    u.pts[i] = ((const float4*)roads)[(size_t)n0 * 40 + i];
  if (t < 32) w4qk_l[t] = W4qk_g[t];
  __syncthreads();

  // ---- pool: 2 threads per (seg,h), 20 pts each; no max-sub (|scores|<~3)
  {
    const int sh = t >> 1, seg = sh >> 3, h = sh & 7;
    const int p0 = (t & 1) * 20;
    const float wa = w4qk_l[h], wb = w4qk_l[8 + h];
    const float wc = w4qk_l[16 + h], wd = w4qk_l[24 + h];
    float ax = 0.f, ay = 0.f, az = 0.f, den = 0.f;
    int nv = 0;
    for (int p = p0; p < p0 + 20; ++p) {
      const float4 pt = u.pts[seg * 40 + p];
      if (pt.w != 0.f) {
        const float e = __expf(wd + pt.x * wa + pt.y * wb + pt.z * wc);
        ax += e * pt.x; ay += e * pt.y; az += e * pt.z; den += e; ++nv;
      }
    }
    ax += __shfl_xor(ax, 1); ay += __shfl_xor(ay, 1); az += __shfl_xor(az, 1);
    den += __shfl_xor(den, 1); nv += __shfl_xor(nv, 1);
    if ((t & 1) == 0) {
      if (nv == 0) {  // empty seg: reference unmasks pt 0 -> attn=[1,0,...]
        const float4 z = u.pts[seg * 40];
        ax = z.x; ay = z.y; az = z.z; den = 1.f;
      }
      const float inv = 1.f / den;
      const float v[4] = {ax * inv, ay * inv, az * inv, 1.f};
      ushort4 hi, lo;
      unsigned short* hp = (unsigned short*)&hi;
      unsigned short* lp = (unsigned short*)&lo;
#pragma unroll
      for (int c = 0; c < 4; ++c) { hp[c] = f2bf(v[c]); lp[c] = f2bf(v[c] - bf2f(hp[c])); }
      // A-frag slot: m=seg, k=h*4+c -> lane=(h>>1)*16+seg, j=(h&1)*4+c
      const int slot = ((h >> 1) * 16 + seg) * 8 + (h & 1) * 4;
      *(ushort4*)&ApF[slot] = hi;
      *(ushort4*)&ApF[512 + slot] = lo;
      if (h == 0) out[OUT0 + n0 + seg] = (nv == 0) ? 1.f : 0.f;
    }
  }
  __syncthreads();

  const int w = t >> 6, lane = t & 63;
  const int quad = lane >> 4, nlane = lane & 15;

  // ---- emb = apool @ T + out_b (MFMA, K=32); wave w owns cols w*32..+31
  float embv[2][4];  // [n2][r]
  {
    const bf16x8 ahi = *(const bf16x8*)&ApF[lane * 8];
    const bf16x8 alo = *(const bf16x8*)&ApF[512 + lane * 8];
#pragma unroll
    for (int n2 = 0; n2 < 2; ++n2) {
      const int nt = w * 2 + n2;
      const unsigned short* tp = Tf + (size_t)nt * 1024;
      const bf16x8 bhi = *(const bf16x8*)(tp + lane * 8);
      const bf16x8 blo = *(const bf16x8*)(tp + 512 + lane * 8);
      f32x4 acc = (f32x4){0.f, 0.f, 0.f, 0.f};
      acc = MFMA16(alo, bhi, acc);
      acc = MFMA16(ahi, blo, acc);
      acc = MFMA16(ahi, bhi, acc);
      const float ob = out_b[nt * 16 + nlane];
#pragma unroll
      for (int r = 0; r < 4; ++r) embv[n2][r] = acc[r] + ob;
    }
    // LN1 partials: per row, sum over this wave's 2 cols then 16 nlanes
#pragma unroll
    for (int r = 0; r < 4; ++r) {
      float s = embv[0][r] + embv[1][r];
      float v = embv[0][r] * embv[0][r] + embv[1][r] * embv[1][r];
#pragma unroll
      for (int m = 1; m < 16; m <<= 1) { s += __shfl_xor(s, m); v += __shfl_xor(v, m); }
      if (nlane == 0) { lnr[quad * 4 + r][w][0] = s; lnr[quad * 4 + r][w][1] = v; }
    }
  }
  __syncthreads();
  // ---- LN1 apply + write emb to A1 (A-frag hi/lo)
#pragma unroll
  for (int r = 0; r < 4; ++r) {
    const int row = quad * 4 + r;
    const float mu = (lnr[row][0][0] + lnr[row][1][0] + lnr[row][2][0] + lnr[row][3][0]) * (1.f / 128.f);
    const float msq = (lnr[row][0][1] + lnr[row][1][1] + lnr[row][2][1] + lnr[row][3][1]) * (1.f / 128.f);
    const float rstd = rsqrtf(msq - mu * mu + 1e-5f);
#pragma unroll
    for (int n2 = 0; n2 < 2; ++n2) {
      const int col = (w * 2 + n2) * 16 + nlane;
      const float e = (embv[n2][r] - mu) * rstd * ln1_g[col] + ln1_b[col];
      const unsigned short hh = f2bf(e), hl = f2bf(e - bf2f(hh));
      const int kk = col >> 5, q2 = (col >> 3) & 3, j = col & 7;
      const int idx = kk * 512 + (q2 * 16 + row) * 8 + j;
      A1[idx] = hh; A1[2048 + idx] = hl;
    }
  }
  __syncthreads();

  // ---- GEMM1: hidden = relu(emb @ w1 + b1); wave w owns nt w*6..w*6+5
#pragma unroll
  for (int nti = 0; nti < 6; ++nti) {
    const int nt = w * 6 + nti;
    f32x4 acc = (f32x4){0.f, 0.f, 0.f, 0.f};
#pragma unroll
    for (int kk = 0; kk < 4; ++kk) {
      const bf16x8 ahi = *(const bf16x8*)&A1[kk * 512 + lane * 8];
      const bf16x8 alo = *(const bf16x8*)&A1[2048 + kk * 512 + lane * 8];
      const unsigned short* wp = w1f + (size_t)(nt * 4 + kk) * 1024;
      const bf16x8 bhi = *(const bf16x8*)(wp + lane * 8);
      const bf16x8 blo = *(const bf16x8*)(wp + 512 + lane * 8);
      acc = MFMA16(alo, bhi, acc);
      acc = MFMA16(ahi, blo, acc);
      acc = MFMA16(ahi, bhi, acc);
    }
    const int col = nt * 16 + nlane;
    const float bias = b1[col];
    const int kk2 = col >> 5, qA = (col >> 3) & 3, jA = col & 7;
#pragma unroll
    for (int r = 0; r < 4; ++r) {
      const float h = fmaxf(acc[r] + bias, 0.f);
      const unsigned short hh = f2bf(h), hl = f2bf(h - bf2f(hh));
      const int idx = kk2 * 512 + (qA * 16 + quad * 4 + r) * 8 + jA;
      u.A2[idx] = hh; u.A2[12288 + idx] = hl;
    }
  }
  __syncthreads();

  // ---- GEMM2: y = hidden @ w2; wave w owns cols w*32..+31 (nt2 = w*2+n2)
  f32x4 acc2[2];
  acc2[0] = (f32x4){0.f, 0.f, 0.f, 0.f};
  acc2[1] = (f32x4){0.f, 0.f, 0.f, 0.f};
#pragma unroll 4
  for (int kk2 = 0; kk2 < 12; ++kk2) {
    const bf16x8 ahi = *(const bf16x8*)&u.A2[kk2 * 512 + lane * 8];
    const bf16x8 alo = *(const bf16x8*)&u.A2[12288 + kk2 * 512 + lane * 8];
#pragma unroll
    for (int n2 = 0; n2 < 2; ++n2) {
      const unsigned short* wp = w2f + (size_t)((w * 2 + n2) * 12 + kk2) * 1024;
      const bf16x8 bhi = *(const bf16x8*)(wp + lane * 8);
      const bf16x8 blo = *(const bf16x8*)(wp + 512 + lane * 8);
      acc2[n2] = MFMA16(alo, bhi, acc2[n2]);
      acc2[n2] = MFMA16(ahi, blo, acc2[n2]);
      acc2[n2] = MFMA16(ahi, bhi, acc2[n2]);
    }
  }

  // ---- epilogue: bias + residual + LN2 + store
  float y[2][4];
#pragma unroll
  for (int n2 = 0; n2 < 2; ++n2) {
    const int col = (w * 2 + n2) * 16 + nlane;
    const float bb = b2[col];
    const int kk = col >> 5, q2 = (col >> 3) & 3, j = col & 7;
#pragma unroll
    for (int r = 0; r < 4; ++r) {
      const int idx = kk * 512 + (q2 * 16 + quad * 4 + r) * 8 + j;
      y[n2][r] = acc2[n2][r] + bb + bf2f(A1[idx]) + bf2f(A1[2048 + idx]);
    }
  }
#pragma unroll
  for (int r = 0; r < 4; ++r) {
    float s = y[0][r] + y[1][r];
    float v = y[0][r] * y[0][r] + y[1][r] * y[1][r];
#pragma unroll
    for (int m = 1; m < 16; m <<= 1) { s += __shfl_xor(s, m); v += __shfl_xor(v, m); }
    if (nlane == 0) { lnr[quad * 4 + r][w][0] = s; lnr[quad * 4 + r][w][1] = v; }
  }
  __syncthreads();
#pragma unroll
  for (int r = 0; r < 4; ++r) {
    const int row = quad * 4 + r;
    const float mu = (lnr[row][0][0] + lnr[row][1][0] + lnr[row][2][0] + lnr[row][3][0]) * (1.f / 128.f);
    const float msq = (lnr[row][0][1] + lnr[row][1][1] + lnr[row][2][1] + lnr[row][3][1]) * (1.f / 128.f);
    const float rstd = rsqrtf(msq - mu * mu + 1e-5f);
    const int n = n0 + row, si = n % 100, bm = n / 100;
#pragma unroll
    for (int n2 = 0; n2 < 2; ++n2) {
      const int col = (w * 2 + n2) * 16 + nlane;
      out[(size_t)si * 16384 + bm * 128 + col] =
          (y[n2][r] - mu) * rstd * ln2_g[col] + ln2_b[col];
    }
  }
}

// ---------------------------------------------------------------------------
// K2: all_seg fix. 128 blocks (one per bm) x 64 thr, wave ballot.
// ---------------------------------------------------------------------------
__global__ void k2_fix_segmask(float* __restrict__ out) {
  const int bm = blockIdx.x, t = threadIdx.x;
  const float* base = out + OUT0 + bm * Sn;
  const float a = base[t];
  const float b = (t < 36) ? base[64 + t] : 0.f;
  const unsigned long long m = __ballot((a != 0.f) || (b != 0.f));
  if (t == 0 && m == 0ULL) out[OUT0 + bm * Sn] = 0.f;
}

extern "C" void kernel_launch(void* const* d_in, const int* in_sizes, int n_in,
                              void* d_out, int out_size, void* d_ws, size_t ws_size,
                              hipStream_t stream) {
  const float* roads = (const float*)d_in[0];
  const float* ms    = (const float*)d_in[2];
  const float* lin_w = (const float*)d_in[3];
  const float* lin_b = (const float*)d_in[4];
  const float* wq    = (const float*)d_in[5];
  const float* wk    = (const float*)d_in[6];
  const float* wv    = (const float*)d_in[7];
  const float* bq    = (const float*)d_in[8];
  const float* bk    = (const float*)d_in[9];
  const float* bv    = (const float*)d_in[10];
  const float* out_w = (const float*)d_in[11];
  const float* out_b = (const float*)d_in[12];
  const float* ln1_g = (const float*)d_in[13];
  const float* ln1_b = (const float*)d_in[14];
  const float* w1    = (const float*)d_in[15];
  const float* b1    = (const float*)d_in[16];
  const float* w2    = (const float*)d_in[17];
  const float* b2    = (const float*)d_in[18];
  const float* ln2_g = (const float*)d_in[19];
  const float* ln2_b = (const float*)d_in[20];

  float* out  = (float*)d_out;
  float* W4qk = (float*)d_ws;                          // 32 f
  unsigned short* w1f = (unsigned short*)(W4qk + 32);  // 192 KiB
  unsigned short* w2f = w1f + 96 * 1024;               // 192 KiB
  unsigned short* Tf  = w2f + 96 * 1024;               // 16 KiB

  k0m<<<49, 256, 0, stream>>>(ms, wq, wk, bq, bk, lin_w, lin_b, wv, bv, out_w,
                              w1, w2, W4qk, w1f, w2f, Tf);
  k_all<<<Nn / 16, 256, 0, stream>>>(roads, W4qk, Tf, out_b, ln1_g, ln1_b,
                                     w1f, w2f, b1, b2, ln2_g, ln2_b, out);
  k2_fix_segmask<<<128, 64, 0, stream>>>(out);
}

// Round 10
// 134.259 us; speedup vs baseline: 1.1283x; 1.1283x over previous
//
#include <hip/hip_runtime.h>

// B=16, M=8, S=100, P=40, A=3, D=128, H=8, HD=16. Inputs fp32, output fp32.
// Algebra: feats = [a0,a1,a2,1] @ W4 (rank-4) =>
//   scores = pts4 @ W4qk (4x8); apool[seg,h,j] = softmax-pool of pts4 (K=32);
//   emb_pre = apool @ T + out_b  (T = 32x128, precomputed; MFMA K=32)
// Single fused kernel: pool -> emb MFMA -> LN1 -> FFN MFMA -> LN2.
// All GEMMs in bf16 hi/lo split (3 products) for fp32-grade accuracy.
// R7 configuration restored verbatim (best measured: 135.8 us).
// R8 lesson: G=32 fatter blocks regressed (occupancy loss beats L2 saving).
// R9 lesson: merged k0m regressed vs split k0+k0b (or noise); split is best-known.
namespace {
constexpr int Sn = 100;
constexpr int Nn = 12800;               // B*M*S
constexpr int OUT0 = 1638400;           // S*B*M*D
}

using bf16x8 = __attribute__((ext_vector_type(8))) short;
using f32x4  = __attribute__((ext_vector_type(4))) float;
#define MFMA16(a, b, c) __builtin_amdgcn_mfma_f32_16x16x32_bf16((a), (b), (c), 0, 0, 0)

__device__ __forceinline__ unsigned short f2bf(float x) {
  unsigned int u = __float_as_uint(x);
  return (unsigned short)((u + 0x7FFFu + ((u >> 16) & 1u)) >> 16);
}
__device__ __forceinline__ float bf2f(unsigned short h) {
  return __uint_as_float(((unsigned int)h) << 16);
}

// ---------------------------------------------------------------------------
// K0: 40 blocks x 128 thr. Blocks 0..7: W4qk column h. Blocks 8..39: T row hj.
// ---------------------------------------------------------------------------
__global__ __launch_bounds__(128) void k0_precompute(
    const float* __restrict__ ms, const float* __restrict__ wq,
    const float* __restrict__ wk, const float* __restrict__ bq,
    const float* __restrict__ bk, const float* __restrict__ lin_w,
    const float* __restrict__ lin_b, const float* __restrict__ wv,
    const float* __restrict__ bv, const float* __restrict__ out_w,
    float* __restrict__ W4qk, float* __restrict__ T) {
  const int t = threadIdx.x;
  if (blockIdx.x < 8) {
    const int h = blockIdx.x;
    __shared__ float q[128];
    __shared__ float qkh[128];
    __shared__ float qbkh;
    __shared__ float part[128];
    float s = bq[t];
    for (int c = 0; c < 128; ++c) s += ms[c] * wq[c * 128 + t];
    q[t] = s;
    __syncthreads();
    float a = 0.f;
#pragma unroll
    for (int j = 0; j < 16; ++j) a += q[h * 16 + j] * wk[t * 128 + h * 16 + j];
    qkh[t] = a * 0.25f;
    if (t == 0) {
      float b = 0.f;
#pragma unroll
      for (int j = 0; j < 16; ++j) b += q[h * 16 + j] * bk[h * 16 + j];
      qbkh = b * 0.25f;
    }
    __syncthreads();
    const int j = t >> 5, cp = t & 31;
    float p = 0.f;
    for (int c = cp * 4; c < cp * 4 + 4; ++c) {
      const float w4 = (j < 3) ? lin_w[j * 128 + c] : lin_b[c];
      p += w4 * qkh[c];
    }
    part[t] = p;
    __syncthreads();
    if (t < 4) {
      float sum = 0.f;
      for (int i = 0; i < 32; ++i) sum += part[t * 32 + i];
      if (t == 3) sum += qbkh;
      W4qk[t * 8 + h] = sum;
    }
  } else {
    const int hj = blockIdx.x - 8;            // 0..31
    const int h = hj >> 2, j = hj & 3;
    __shared__ float part[128];
    __shared__ float w4wv[16];
    const int cp = t & 7;
    float p = 0.f;
    for (int c = cp * 16; c < cp * 16 + 16; ++c) {
      const float w4 = (j < 3) ? lin_w[j * 128 + c] : lin_b[c];
      p += w4 * wv[c * 128 + (h * 16 + (t >> 3))];
    }
    part[t] = p;
    __syncthreads();
    if (t < 16) {
      float sum = 0.f;
      for (int i = 0; i < 8; ++i) sum += part[t * 8 + i];
      if (j == 3) sum += bv[h * 16 + t];
      w4wv[t] = sum;
    }
    __syncthreads();
    float acc = 0.f;
#pragma unroll
    for (int e2 = 0; e2 < 16; ++e2) acc += w4wv[e2] * out_w[(h * 16 + e2) * 128 + t];
    T[hj * 128 + t] = acc;
  }
}

// ---------------------------------------------------------------------------
// K0b: repack w1 (128x384), w2 (384x128), T (32x128) into bf16 hi/lo
// B-frag-major tiles. Tile (nt,kk): 16 cols x 32 k; slot [tile][hl][lane][j8],
// lane = (k/8)*16 + n%16. 50 blocks x 256 thr (200 tiles x 64 lanes).
// ---------------------------------------------------------------------------
__global__ __launch_bounds__(256) void k0b_repack(
    const float* __restrict__ w1, const float* __restrict__ w2,
    const float* __restrict__ T,
    unsigned short* __restrict__ w1f, unsigned short* __restrict__ w2f,
    unsigned short* __restrict__ Tf) {
  const int gid = blockIdx.x * 256 + threadIdx.x;
  const int tile = gid >> 6, lane = gid & 63;
  const int quad = lane >> 4, n16 = lane & 15;
  unsigned short hi[8], lo[8];
  unsigned short* dst;
  if (tile < 96) {                 // w1: nt 0..23, kk 0..3
    const int nt = tile >> 2, kk = tile & 3;
    const int n = nt * 16 + n16;
#pragma unroll
    for (int j = 0; j < 8; ++j) {
      const int k = kk * 32 + quad * 8 + j;
      const float v = w1[k * 384 + n];
      hi[j] = f2bf(v); lo[j] = f2bf(v - bf2f(hi[j]));
    }
    dst = w1f + (size_t)tile * 1024 + lane * 8;
  } else if (tile < 192) {         // w2: nt2 0..7, kk2 0..11
    const int t2 = tile - 96;
    const int nt2 = t2 / 12, kk2 = t2 % 12;
    const int n = nt2 * 16 + n16;
#pragma unroll
    for (int j = 0; j < 8; ++j) {
      const int k = kk2 * 32 + quad * 8 + j;
      const float v = w2[k * 128 + n];
      hi[j] = f2bf(v); lo[j] = f2bf(v - bf2f(hi[j]));
    }
    dst = w2f + (size_t)(tile - 96) * 1024 + lane * 8;
  } else {                         // T: nt 0..7, K=32 single kk
    const int nt = tile - 192;
    const int n = nt * 16 + n16;
#pragma unroll
    for (int j = 0; j < 8; ++j) {
      const int k = quad * 8 + j;
      const float v = T[k * 128 + n];
      hi[j] = f2bf(v); lo[j] = f2bf(v - bf2f(hi[j]));
    }
    dst = Tf + (size_t)nt * 1024 + lane * 8;
  }
#pragma unroll
  for (int j = 0; j < 8; ++j) { dst[j] = hi[j]; dst[512 + j] = lo[j]; }
}

// ---------------------------------------------------------------------------
// K_ALL: fully fused. 800 blocks x 256 thr, 16 segments each.
// pool (VALU) -> emb = apool@Tf (MFMA,K=32) + LN1 -> FFN MFMA + LN2 -> out.
// ---------------------------------------------------------------------------
__global__ __launch_bounds__(256) void k_all(
    const float* __restrict__ roads, const float* __restrict__ W4qk_g,
    const unsigned short* __restrict__ Tf, const float* __restrict__ out_b,
    const float* __restrict__ ln1_g, const float* __restrict__ ln1_b,
    const unsigned short* __restrict__ w1f, const unsigned short* __restrict__ w2f,
    const float* __restrict__ b1, const float* __restrict__ b2,
    const float* __restrict__ ln2_g, const float* __restrict__ ln2_b,
    float* __restrict__ out) {
  const int t = threadIdx.x;
  const int n0 = blockIdx.x * 16;

  __shared__ union {
    float4 pts[640];                         // 10 KB (dead after pool)
    __align__(16) unsigned short A2[24576];  // hidden 16x384 hi/lo, 24 KB
  } u;
  __shared__ __align__(16) unsigned short A1[4096];   // emb 16x128 hi/lo, 8 KB
  __shared__ __align__(16) unsigned short ApF[1024];  // apool 16x32 hi/lo, 2 KB
  __shared__ float w4qk_l[32];
  __shared__ float lnr[16][4][2];

  // ---- stage pts + folded QK
  for (int i = t; i < 640; i += 256)
    u.pts[i] = ((const float4*)roads)[(size_t)n0 * 40 + i];
  if (t < 32) w4qk_l[t] = W4qk_g[t];
  __syncthreads();

  // ---- pool: 2 threads per (seg,h), 20 pts each; no max-sub (|scores|<~3)
  {
    const int sh = t >> 1, seg = sh >> 3, h = sh & 7;
    const int p0 = (t & 1) * 20;
    const float wa = w4qk_l[h], wb = w4qk_l[8 + h];
    const float wc = w4qk_l[16 + h], wd = w4qk_l[24 + h];
    float ax = 0.f, ay = 0.f, az = 0.f, den = 0.f;
    int nv = 0;
    for (int p = p0; p < p0 + 20; ++p) {
      const float4 pt = u.pts[seg * 40 + p];
      if (pt.w != 0.f) {
        const float e = __expf(wd + pt.x * wa + pt.y * wb + pt.z * wc);
        ax += e * pt.x; ay += e * pt.y; az += e * pt.z; den += e; ++nv;
      }
    }
    ax += __shfl_xor(ax, 1); ay += __shfl_xor(ay, 1); az += __shfl_xor(az, 1);
    den += __shfl_xor(den, 1); nv += __shfl_xor(nv, 1);
    if ((t & 1) == 0) {
      if (nv == 0) {  // empty seg: reference unmasks pt 0 -> attn=[1,0,...]
        const float4 z = u.pts[seg * 40];
        ax = z.x; ay = z.y; az = z.z; den = 1.f;
      }
      const float inv = 1.f / den;
      const float v[4] = {ax * inv, ay * inv, az * inv, 1.f};
      ushort4 hi, lo;
      unsigned short* hp = (unsigned short*)&hi;
      unsigned short* lp = (unsigned short*)&lo;
#pragma unroll
      for (int c = 0; c < 4; ++c) { hp[c] = f2bf(v[c]); lp[c] = f2bf(v[c] - bf2f(hp[c])); }
      // A-frag slot: m=seg, k=h*4+c -> quad=h>>1, j=(h&1)*4+c
      const int slot = ((h >> 1) * 16 + seg) * 8 + (h & 1) * 4;
      *(ushort4*)&ApF[slot] = hi;
      *(ushort4*)&ApF[512 + slot] = lo;
      if (h == 0) out[OUT0 + n0 + seg] = (nv == 0) ? 1.f : 0.f;
    }
  }
  __syncthreads();

  const int w = t >> 6, lane = t & 63;
  const int quad = lane >> 4, nlane = lane & 15;

  // ---- emb = apool @ T + out_b (MFMA, K=32); wave w owns cols w*32..+31
  float embv[2][4];  // [n2][r]
  {
    const bf16x8 ahi = *(const bf16x8*)&ApF[lane * 8];
    const bf16x8 alo = *(const bf16x8*)&ApF[512 + lane * 8];
#pragma unroll
    for (int n2 = 0; n2 < 2; ++n2) {
      const int nt = w * 2 + n2;
      const unsigned short* tp = Tf + (size_t)nt * 1024;
      const bf16x8 bhi = *(const bf16x8*)(tp + lane * 8);
      const bf16x8 blo = *(const bf16x8*)(tp + 512 + lane * 8);
      f32x4 acc = (f32x4){0.f, 0.f, 0.f, 0.f};
      acc = MFMA16(alo, bhi, acc);
      acc = MFMA16(ahi, blo, acc);
      acc = MFMA16(ahi, bhi, acc);
      const float ob = out_b[nt * 16 + nlane];
#pragma unroll
      for (int r = 0; r < 4; ++r) embv[n2][r] = acc[r] + ob;
    }
    // LN1 partials: per row, sum over this wave's 2 cols then 16 nlanes
#pragma unroll
    for (int r = 0; r < 4; ++r) {
      float s = embv[0][r] + embv[1][r];
      float v = embv[0][r] * embv[0][r] + embv[1][r] * embv[1][r];
#pragma unroll
      for (int m = 1; m < 16; m <<= 1) { s += __shfl_xor(s, m); v += __shfl_xor(v, m); }
      if (nlane == 0) { lnr[quad * 4 + r][w][0] = s; lnr[quad * 4 + r][w][1] = v; }
    }
  }
  __syncthreads();
  // ---- LN1 apply + write emb to A1 (A-frag hi/lo)
#pragma unroll
  for (int r = 0; r < 4; ++r) {
    const int row = quad * 4 + r;
    const float mu = (lnr[row][0][0] + lnr[row][1][0] + lnr[row][2][0] + lnr[row][3][0]) * (1.f / 128.f);
    const float msq = (lnr[row][0][1] + lnr[row][1][1] + lnr[row][2][1] + lnr[row][3][1]) * (1.f / 128.f);
    const float rstd = rsqrtf(msq - mu * mu + 1e-5f);
#pragma unroll
    for (int n2 = 0; n2 < 2; ++n2) {
      const int col = (w * 2 + n2) * 16 + nlane;
      const float e = (embv[n2][r] - mu) * rstd * ln1_g[col] + ln1_b[col];
      const unsigned short hh = f2bf(e), hl = f2bf(e - bf2f(hh));
      const int kk = col >> 5, q2 = (col >> 3) & 3, j = col & 7;
      const int idx = kk * 512 + (q2 * 16 + row) * 8 + j;
      A1[idx] = hh; A1[2048 + idx] = hl;
    }
  }
  __syncthreads();

  // ---- GEMM1: hidden = relu(emb @ w1 + b1); wave w owns nt w*6..w*6+5
#pragma unroll
  for (int nti = 0; nti < 6; ++nti) {
    const int nt = w * 6 + nti;
    f32x4 acc = (f32x4){0.f, 0.f, 0.f, 0.f};
#pragma unroll
    for (int kk = 0; kk < 4; ++kk) {
      const bf16x8 ahi = *(const bf16x8*)&A1[kk * 512 + lane * 8];
      const bf16x8 alo = *(const bf16x8*)&A1[2048 + kk * 512 + lane * 8];
      const unsigned short* wp = w1f + (size_t)(nt * 4 + kk) * 1024;
      const bf16x8 bhi = *(const bf16x8*)(wp + lane * 8);
      const bf16x8 blo = *(const bf16x8*)(wp + 512 + lane * 8);
      acc = MFMA16(alo, bhi, acc);
      acc = MFMA16(ahi, blo, acc);
      acc = MFMA16(ahi, bhi, acc);
    }
    const int col = nt * 16 + nlane;
    const float bias = b1[col];
    const int kk2 = col >> 5, qA = (col >> 3) & 3, jA = col & 7;
#pragma unroll
    for (int r = 0; r < 4; ++r) {
      const float h = fmaxf(acc[r] + bias, 0.f);
      const unsigned short hh = f2bf(h), hl = f2bf(h - bf2f(hh));
      const int idx = kk2 * 512 + (qA * 16 + quad * 4 + r) * 8 + jA;
      u.A2[idx] = hh; u.A2[12288 + idx] = hl;
    }
  }
  __syncthreads();

  // ---- GEMM2: y = hidden @ w2; wave w owns cols w*32..+31 (nt2 = w*2+n2)
  f32x4 acc2[2];
  acc2[0] = (f32x4){0.f, 0.f, 0.f, 0.f};
  acc2[1] = (f32x4){0.f, 0.f, 0.f, 0.f};
#pragma unroll 4
  for (int kk2 = 0; kk2 < 12; ++kk2) {
    const bf16x8 ahi = *(const bf16x8*)&u.A2[kk2 * 512 + lane * 8];
    const bf16x8 alo = *(const bf16x8*)&u.A2[12288 + kk2 * 512 + lane * 8];
#pragma unroll
    for (int n2 = 0; n2 < 2; ++n2) {
      const unsigned short* wp = w2f + (size_t)((w * 2 + n2) * 12 + kk2) * 1024;
      const bf16x8 bhi = *(const bf16x8*)(wp + lane * 8);
      const bf16x8 blo = *(const bf16x8*)(wp + 512 + lane * 8);
      acc2[n2] = MFMA16(alo, bhi, acc2[n2]);
      acc2[n2] = MFMA16(ahi, blo, acc2[n2]);
      acc2[n2] = MFMA16(ahi, bhi, acc2[n2]);
    }
  }

  // ---- epilogue: bias + residual + LN2 + store
  float y[2][4];
#pragma unroll
  for (int n2 = 0; n2 < 2; ++n2) {
    const int col = (w * 2 + n2) * 16 + nlane;
    const float bb = b2[col];
    const int kk = col >> 5, q2 = (col >> 3) & 3, j = col & 7;
#pragma unroll
    for (int r = 0; r < 4; ++r) {
      const int idx = kk * 512 + (q2 * 16 + quad * 4 + r) * 8 + j;
      y[n2][r] = acc2[n2][r] + bb + bf2f(A1[idx]) + bf2f(A1[2048 + idx]);
    }
  }
#pragma unroll
  for (int r = 0; r < 4; ++r) {
    float s = y[0][r] + y[1][r];
    float v = y[0][r] * y[0][r] + y[1][r] * y[1][r];
#pragma unroll
    for (int m = 1; m < 16; m <<= 1) { s += __shfl_xor(s, m); v += __shfl_xor(v, m); }
    if (nlane == 0) { lnr[quad * 4 + r][w][0] = s; lnr[quad * 4 + r][w][1] = v; }
  }
  __syncthreads();
#pragma unroll
  for (int r = 0; r < 4; ++r) {
    const int row = quad * 4 + r;
    const float mu = (lnr[row][0][0] + lnr[row][1][0] + lnr[row][2][0] + lnr[row][3][0]) * (1.f / 128.f);
    const float msq = (lnr[row][0][1] + lnr[row][1][1] + lnr[row][2][1] + lnr[row][3][1]) * (1.f / 128.f);
    const float rstd = rsqrtf(msq - mu * mu + 1e-5f);
    const int n = n0 + row, si = n % 100, bm = n / 100;
#pragma unroll
    for (int n2 = 0; n2 < 2; ++n2) {
      const int col = (w * 2 + n2) * 16 + nlane;
      out[(size_t)si * 16384 + bm * 128 + col] =
          (y[n2][r] - mu) * rstd * ln2_g[col] + ln2_b[col];
    }
  }
}

// ---------------------------------------------------------------------------
// K2: all_seg fix. 128 blocks (one per bm) x 64 thr, wave ballot.
// ---------------------------------------------------------------------------
__global__ void k2_fix_segmask(float* __restrict__ out) {
  const int bm = blockIdx.x, t = threadIdx.x;
  const float* base = out + OUT0 + bm * Sn;
  const float a = base[t];
  const float b = (t < 36) ? base[64 + t] : 0.f;
  const unsigned long long m = __ballot((a != 0.f) || (b != 0.f));
  if (t == 0 && m == 0ULL) out[OUT0 + bm * Sn] = 0.f;
}

extern "C" void kernel_launch(void* const* d_in, const int* in_sizes, int n_in,
                              void* d_out, int out_size, void* d_ws, size_t ws_size,
                              hipStream_t stream) {
  const float* roads = (const float*)d_in[0];
  const float* ms    = (const float*)d_in[2];
  const float* lin_w = (const float*)d_in[3];
  const float* lin_b = (const float*)d_in[4];
  const float* wq    = (const float*)d_in[5];
  const float* wk    = (const float*)d_in[6];
  const float* wv    = (const float*)d_in[7];
  const float* bq    = (const float*)d_in[8];
  const float* bk    = (const float*)d_in[9];
  const float* bv    = (const float*)d_in[10];
  const float* out_w = (const float*)d_in[11];
  const float* out_b = (const float*)d_in[12];
  const float* ln1_g = (const float*)d_in[13];
  const float* ln1_b = (const float*)d_in[14];
  const float* w1    = (const float*)d_in[15];
  const float* b1    = (const float*)d_in[16];
  const float* w2    = (const float*)d_in[17];
  const float* b2    = (const float*)d_in[18];
  const float* ln2_g = (const float*)d_in[19];
  const float* ln2_b = (const float*)d_in[20];

  float* out  = (float*)d_out;
  float* W4qk = (float*)d_ws;                         // 32 f
  float* T    = W4qk + 32;                            // 4096 f
  unsigned short* w1f = (unsigned short*)(T + 4096);  // 192 KiB
  unsigned short* w2f = w1f + 96 * 1024;              // 192 KiB
  unsigned short* Tf  = w2f + 96 * 1024;              // 16 KiB

  k0_precompute<<<40, 128, 0, stream>>>(ms, wq, wk, bq, bk, lin_w, lin_b, wv, bv, out_w, W4qk, T);
  k0b_repack<<<50, 256, 0, stream>>>(w1, w2, T, w1f, w2f, Tf);
  k_all<<<Nn / 16, 256, 0, stream>>>(roads, W4qk, Tf, out_b, ln1_g, ln1_b,
                                     w1f, w2f, b1, b2, ln2_g, ln2_b, out);
  k2_fix_segmask<<<128, 64, 0, stream>>>(out);
}